// Round 16
// baseline (254.732 us; speedup 1.0000x reference)
//
#include <hip/hip_runtime.h>
#include <hip/hip_fp16.h>
#include <math.h>

#define NEG_SLOPE 0.2f
#define EPS_F 1e-16f

// CSR-build geometry: coarse bucket = dst>>7 (128 locals/bucket).
// nbucket = 782 for N=100000 (<=1024); src < 2^23.
#define P1_NB 256        // pass-1 chunks (hist/scatter blocks)
#define P1S_THREADS 1024 // hist/scatter threads: 16 waves/CU for latency hiding
#define MAX_BEDGES 5120  // LDS edge cap per bucket (mean ~4100, ~16 sigma margin)

__device__ __forceinline__ float leaky(float v) {
    return v >= 0.f ? v : NEG_SLOPE * v;
}

// ---------------- Fused: phaseA (blocks 0..nodeb16-1, 16 nodes each) +
//                  p1hist (last P1_NB blocks, R13-proven 1024-thr geometry) ----
__global__ void k_fusedA(const float* __restrict__ x, const float* __restrict__ W1,
                         const float* __restrict__ a_src1, const float* __restrict__ a_dst1,
                         __half* __restrict__ h1h, float* __restrict__ as1,
                         float* __restrict__ ad1, int N, int nodeb16,
                         const int* __restrict__ dst, int* __restrict__ histT,
                         int E, int chunk, int nbucket) {
    __shared__ int cnt[1024];
    if (blockIdx.x < (unsigned)nodeb16) {
        int node = blockIdx.x * 16 + (threadIdx.x >> 6);
        if (node >= N) return;
        int lane = threadIdx.x & 63;
        float x0 = x[node * 4 + 0], x1 = x[node * 4 + 1];
        float x2 = x[node * 4 + 2], x3 = x[node * 4 + 3];
        float h = x0 * W1[lane] + x1 * W1[64 + lane] + x2 * W1[128 + lane] + x3 * W1[192 + lane];
        h1h[(size_t)node * 64 + lane] = __float2half(h);
        float as = h * a_src1[lane];
        float ad = h * a_dst1[lane];
#pragma unroll
        for (int m = 8; m >= 1; m >>= 1) {
            as += __shfl_xor(as, m, 16);
            ad += __shfl_xor(ad, m, 16);
        }
        if ((lane & 15) == 0) {
            int head = lane >> 4;
            as1[node * 4 + head] = as;
            ad1[node * 4 + head] = ad;
        }
    } else {
        int blk = blockIdx.x - nodeb16, t = threadIdx.x;
        for (int i = t; i < nbucket; i += P1S_THREADS) cnt[i] = 0;
        __syncthreads();
        int s = blk * chunk, e = min(E, s + chunk);
        for (int i = s + t; i < e; i += P1S_THREADS)
            atomicAdd(&cnt[dst[i] >> 7], 1);
        __syncthreads();
        for (int i = t; i < nbucket; i += P1S_THREADS)
            histT[i * P1_NB + blk] = cnt[i];             // bin-major
    }
}

// exclusive scan, 2048 elems per block (256 thr x 8)
__global__ void k_scan1(const int* __restrict__ in, int* __restrict__ out,
                        int* __restrict__ blockSums, int M) {
    __shared__ int sdata[256];
    int t = threadIdx.x;
    int base = blockIdx.x * 2048 + t * 8;
    int v[8];
    int total = 0;
#pragma unroll
    for (int k = 0; k < 8; ++k) {
        int idx = base + k;
        v[k] = (idx < M) ? in[idx] : 0;
        total += v[k];
    }
    sdata[t] = total;
    __syncthreads();
    for (int off = 1; off < 256; off <<= 1) {
        int x = (t >= off) ? sdata[t - off] : 0;
        __syncthreads();
        sdata[t] += x;
        __syncthreads();
    }
    int run = sdata[t] - total;
#pragma unroll
    for (int k = 0; k < 8; ++k) {
        int idx = base + k;
        if (idx < M) out[idx] = run;
        run += v[k];
    }
    if (t == 255) blockSums[blockIdx.x] = sdata[255];
}

// fused scan2+scan3: each block computes prefix of blockSums itself (<=128 sums)
__global__ void k_scan23(int* __restrict__ out, const int* __restrict__ blockSums, int M) {
    int t = threadIdx.x;
    int base = blockIdx.x * 2048 + t * 8;
    int off = 0;
    for (int j = 0; j < (int)blockIdx.x; ++j) off += blockSums[j];  // broadcast loads
#pragma unroll
    for (int k = 0; k < 8; ++k) {
        int idx = base + k;
        if (idx < M) out[idx] += off;
    }
}

// 1024 threads: 16 waves/CU hides the LDS-atomic -> scattered-store latency
__global__ void k_p1scatter(const int* __restrict__ src, const int* __restrict__ dst,
                            const int* __restrict__ baseT, unsigned int* __restrict__ packed,
                            int E, int chunk, int nbucket) {
    __shared__ int cnt[1024];
    int blk = blockIdx.x, t = threadIdx.x;
    for (int i = t; i < nbucket; i += P1S_THREADS) cnt[i] = baseT[i * P1_NB + blk];
    __syncthreads();
    int s = blk * chunk, e = min(E, s + chunk);
    for (int i = s + t; i < e; i += P1S_THREADS) {
        int d = dst[i];
        int pos = atomicAdd(&cnt[d >> 7], 1);            // LDS atomic
        packed[pos] = ((unsigned int)(d & 127) << 23) | (unsigned int)src[i];
    }
}

// ---------------- Fused fine + layer1: one block per bucket (782 x 512 thr) --------
// ~22 KB LDS -> 4 blocks/CU (32 waves, 100% occupancy), 782 blocks fit one
// scheduling round (1024 slots) -> balanced, unlike R15's 391x1024 (50% occ).
__global__ void k_fineL1(const unsigned int* __restrict__ packed, const int* __restrict__ baseT,
                         const __half* __restrict__ h1h, const float* __restrict__ as1,
                         const float* __restrict__ ad1, const float* __restrict__ b1,
                         const float* __restrict__ W2, const float* __restrict__ a_src2,
                         const float* __restrict__ a_dst2,
                         int* __restrict__ csr, int* __restrict__ rowptr,
                         float4* __restrict__ node2, int N, int E) {
    __shared__ int cnt[128];                 // per-local degree (preserved)
    __shared__ int off[128];                 // per-local exclusive offset (preserved)
    __shared__ int cur[128];                 // scratch: scan + placement cursor
    __shared__ unsigned int eb[MAX_BEDGES];  // bucket edges sorted by local

    int b = blockIdx.x, t = threadIdx.x;
    int nbucket = gridDim.x;
    int startE = baseT[b * P1_NB];
    int endE = (b == nbucket - 1) ? E : baseT[(b + 1) * P1_NB];
    int ne = endE - startE;
    if (ne > MAX_BEDGES) ne = MAX_BEDGES;    // statistically impossible (~16 sigma)

    if (t < 128) cnt[t] = 0;
    __syncthreads();
    for (int i = t; i < ne; i += 512)
        atomicAdd(&cnt[packed[startE + i] >> 23], 1);
    __syncthreads();
    if (t < 128) cur[t] = cnt[t];
    __syncthreads();
    for (int o = 1; o < 128; o <<= 1) {
        int v = (t < 128 && t >= o) ? cur[t - o] : 0;
        __syncthreads();
        if (t < 128) cur[t] += v;
        __syncthreads();
    }
    if (t < 128) {
        int excl = cur[t] - cnt[t];
        off[t] = excl;
        int node = (b << 7) + t;
        if (node < N) rowptr[node] = startE + excl;
    }
    if (b == 0 && t == 0) rowptr[N] = E;
    __syncthreads();
    if (t < 128) cur[t] = off[t];
    __syncthreads();
    for (int i = t; i < ne; i += 512) {
        unsigned int p = packed[startE + i];
        int pos = atomicAdd(&cur[p >> 23], 1);
        eb[pos] = p;
    }
    __syncthreads();
    // sequential csr writeout (consumed by k_layer2)
    for (int i = t; i < ne; i += 512)
        csr[startE + i] = (int)(eb[i] & 0x7FFFFFu);

    // ---- layer1 over this bucket's 128 nodes (8 waves x 16 locals) ----
    int wave = t >> 6;           // 0..7
    int lane = t & 63;
    int head4 = lane & 3;        // stage-1 head
    int j     = lane >> 2;       // stage-1 edge slot (0..15)
    int sub   = lane >> 4;       // stage-2 edge subgroup (0..3)
    int fl    = lane & 15;       // stage-2 feature quad
    int h     = fl >> 2;         // stage-2 head
    int nodeBase = b << 7;

    for (int q = 0; q < 16; ++q) {
        int local = wave * 16 + q;
        int node = nodeBase + local;
        if (node >= N) break;    // wave-uniform (only last bucket)
        int beg = off[local];
        int end = beg + cnt[local];

        float ad_s1 = ad1[node * 4 + head4];
        float pself4 = __expf(leaky(as1[node * 4 + head4] + ad_s1));
        float psum = (lane < 4) ? pself4 : 0.f;

        float pselfF = __shfl(pself4, h);
        float a0 = 0.f, a1 = 0.f, a2 = 0.f, a3 = 0.f;
        if (sub == 0) {
            float2 raw = *(const float2*)(h1h + ((size_t)node << 6) + (fl << 2));
            __half2 h01 = *reinterpret_cast<__half2*>(&raw.x);
            __half2 h23 = *reinterpret_cast<__half2*>(&raw.y);
            float2 f01 = __half22float2(h01), f23 = __half22float2(h23);
            a0 = pselfF * f01.x; a1 = pselfF * f01.y;
            a2 = pselfF * f23.x; a3 = pselfF * f23.y;
        }

        for (int c = beg; c < end; c += 16) {
            int e = c + j;
            bool valid = e < end;
            int s = (int)(eb[valid ? e : beg] & 0x7FFFFFu);   // LDS broadcast read
            float v = leaky(as1[s * 4 + head4] + ad_s1);
            float p = valid ? __expf(v) : 0.f;
            psum += p;

            int s_q[4];
#pragma unroll
            for (int m = 0; m < 4; ++m) s_q[m] = __shfl(s, m * 16 + sub * 4);
            float2 raw[4];
#pragma unroll
            for (int m = 0; m < 4; ++m)
                raw[m] = *(const float2*)(h1h + ((size_t)s_q[m] << 6) + (fl << 2));
            float p_q[4];
#pragma unroll
            for (int m = 0; m < 4; ++m) p_q[m] = __shfl(p, m * 16 + sub * 4 + h);
#pragma unroll
            for (int m = 0; m < 4; ++m) {
                __half2 h01 = *reinterpret_cast<__half2*>(&raw[m].x);
                __half2 h23 = *reinterpret_cast<__half2*>(&raw[m].y);
                float2 f01 = __half22float2(h01), f23 = __half22float2(h23);
                a0 = fmaf(p_q[m], f01.x, a0);
                a1 = fmaf(p_q[m], f01.y, a1);
                a2 = fmaf(p_q[m], f23.x, a2);
                a3 = fmaf(p_q[m], f23.y, a3);
            }
        }

        a0 += __shfl_xor(a0, 16); a0 += __shfl_xor(a0, 32);
        a1 += __shfl_xor(a1, 16); a1 += __shfl_xor(a1, 32);
        a2 += __shfl_xor(a2, 16); a2 += __shfl_xor(a2, 32);
        a3 += __shfl_xor(a3, 16); a3 += __shfl_xor(a3, 32);

#pragma unroll
        for (int m = 4; m <= 32; m <<= 1) psum += __shfl_xor(psum, m);
        float psumF = __shfl(psum, h);
        float inv = 1.f / (psumF + EPS_F);

        float4 b1v = ((const float4*)b1)[fl];
        float o0 = a0 * inv + b1v.x;
        float o1 = a1 * inv + b1v.y;
        float o2 = a2 * inv + b1v.z;
        float o3 = a3 * inv + b1v.w;
        float e0 = o0 > 0.f ? o0 : expm1f(o0);
        float e1 = o1 > 0.f ? o1 : expm1f(o1);
        float e2 = o2 > 0.f ? o2 : expm1f(o2);
        float e3 = o3 > 0.f ? o3 : expm1f(o3);

        float4 w01 = ((const float4*)W2)[fl * 2];
        float4 w23 = ((const float4*)W2)[fl * 2 + 1];
        float c0 = e0 * w01.x + e1 * w01.z + e2 * w23.x + e3 * w23.z;
        float c1 = e0 * w01.y + e1 * w01.w + e2 * w23.y + e3 * w23.w;
#pragma unroll
        for (int m = 8; m >= 1; m >>= 1) {
            c0 += __shfl_xor(c0, m);
            c1 += __shfl_xor(c1, m);
        }
        if (lane == 0) {
            float as2 = c0 * a_src2[0] + c1 * a_src2[1];
            float ad2 = c0 * a_dst2[0] + c1 * a_dst2[1];
            node2[node] = make_float4(c0, c1, as2, ad2);
        }
    }
}

// ---------------- Layer 2: 16 lanes per node (4 nodes/wave), fused log_softmax ----------------
__global__ void k_layer2(const int* __restrict__ rowptr, const int* __restrict__ csr,
                         const float4* __restrict__ node2, const float* __restrict__ b2,
                         float* __restrict__ out, int N) {
    int node = blockIdx.x * 16 + (threadIdx.x >> 4);
    if (node >= N) return;
    int sl = threadIdx.x & 15;

    float4 me = node2[node];
    float ad = me.w;
    int beg = rowptr[node], end = rowptr[node + 1];

    float psum = 0.f, a0 = 0.f, a1 = 0.f;
    for (int e = beg + sl; e < end; e += 16) {
        float4 sn = node2[csr[e]];
        float p = __expf(leaky(sn.z + ad));
        psum += p;
        a0 = fmaf(p, sn.x, a0);
        a1 = fmaf(p, sn.y, a1);
    }
    if (sl == 0) {
        float p = __expf(leaky(me.z + ad));       // self loop
        psum += p;
        a0 = fmaf(p, me.x, a0);
        a1 = fmaf(p, me.y, a1);
    }
#pragma unroll
    for (int m = 8; m >= 1; m >>= 1) {
        psum += __shfl_xor(psum, m);
        a0 += __shfl_xor(a0, m);
        a1 += __shfl_xor(a1, m);
    }
    if (sl == 0) {
        float inv = 1.f / (psum + EPS_F);
        float o0 = a0 * inv + b2[0];
        float o1 = a1 * inv + b2[1];
        float mx = fmaxf(o0, o1);
        float lse = mx + logf(__expf(o0 - mx) + __expf(o1 - mx));
        out[node * 2 + 0] = o0 - lse;
        out[node * 2 + 1] = o1 - lse;
    }
}

// ---------------- launch ----------------

extern "C" void kernel_launch(void* const* d_in, const int* in_sizes, int n_in,
                              void* d_out, int out_size, void* d_ws, size_t ws_size,
                              hipStream_t stream) {
    const float* x      = (const float*)d_in[0];
    const int*   ei     = (const int*)d_in[1];
    const float* W1     = (const float*)d_in[2];
    const float* a_src1 = (const float*)d_in[3];
    const float* a_dst1 = (const float*)d_in[4];
    const float* b1     = (const float*)d_in[5];
    const float* W2     = (const float*)d_in[6];
    const float* a_src2 = (const float*)d_in[7];
    const float* a_dst2 = (const float*)d_in[8];
    const float* b2     = (const float*)d_in[9];
    float* out = (float*)d_out;

    int N = in_sizes[0] / 4;
    int E = in_sizes[1] / 2;
    const int* e_src = ei;
    const int* e_dst = ei + E;

    int nbucket = (N + 127) >> 7;               // 782 for N=100000 (<=1024)
    int M = nbucket * P1_NB;                    // 200192

    char* w = (char*)d_ws;
    auto alloc = [&](size_t bytes) -> void* {
        void* p = (void*)w;
        w += (bytes + 255) & ~(size_t)255;
        return p;
    };
    __half* h1h       = (__half*)alloc((size_t)N * 64 * 2);
    float*  as1       = (float*)alloc((size_t)N * 4 * 4);
    float*  ad1       = (float*)alloc((size_t)N * 4 * 4);
    float4* node2     = (float4*)alloc((size_t)N * 16);
    int*    rowptr    = (int*)alloc((size_t)(N + 1) * 4);
    int*    histT     = (int*)alloc((size_t)M * 4);
    int*    baseT     = (int*)alloc((size_t)M * 4);
    int*    blockSums = (int*)alloc(256 * 4);
    int*    csr       = (int*)alloc((size_t)E * 4);
    unsigned int* packed = (unsigned int*)alloc((size_t)E * 4);

    int chunk = (E + P1_NB - 1) / P1_NB;        // 12500
    int nbScan = (M + 2047) / 2048;             // 98 (<=256)
    int nodeb16 = (N + 15) / 16;                // 6250

    k_fusedA<<<nodeb16 + P1_NB, 1024, 0, stream>>>(x, W1, a_src1, a_dst1, h1h, as1, ad1,
                                                   N, nodeb16, e_dst, histT, E, chunk, nbucket);
    k_scan1<<<nbScan, 256, 0, stream>>>(histT, baseT, blockSums, M);
    k_scan23<<<nbScan, 256, 0, stream>>>(baseT, blockSums, M);
    k_p1scatter<<<P1_NB, P1S_THREADS, 0, stream>>>(e_src, e_dst, baseT, packed, E, chunk, nbucket);
    k_fineL1<<<nbucket, 512, 0, stream>>>(packed, baseT, h1h, as1, ad1, b1, W2,
                                          a_src2, a_dst2, csr, rowptr, node2, N, E);
    k_layer2<<<(N + 15) / 16, 256, 0, stream>>>(rowptr, csr, node2, b2, out, N);
}

// Round 17
// 243.483 us; speedup vs baseline: 1.0462x; 1.0462x over previous
//
#include <hip/hip_runtime.h>
#include <hip/hip_fp16.h>
#include <math.h>

#define NEG_SLOPE 0.2f
#define EPS_F 1e-16f

// CSR-build geometry: coarse bucket = dst>>8 (256 locals/bucket).
// nbucket = 391 for N=100000 (<=512); src < 2^23.
#define P1_NB 256        // pass-1 chunks (hist/scatter blocks)
#define P1S_THREADS 1024 // hist/scatter threads: 16 waves/CU for latency hiding
#define MAX_BEDGES 10240 // LDS edge cap per bucket (mean ~8200, ~23 sigma margin)
#define SCAN_SHIFT 11    // scan1 handles 2048 elements per block

__device__ __forceinline__ float leaky(float v) {
    return v >= 0.f ? v : NEG_SLOPE * v;
}

// ---------------- Phase A: h1 = x @ W1 (fp16 out), alpha_src1/alpha_dst1 ----------------
__global__ void k_phaseA(const float* __restrict__ x, const float* __restrict__ W1,
                         const float* __restrict__ a_src1, const float* __restrict__ a_dst1,
                         __half* __restrict__ h1h, float* __restrict__ as1,
                         float* __restrict__ ad1, int N) {
    int node = blockIdx.x * 4 + (threadIdx.x >> 6);
    if (node >= N) return;
    int lane = threadIdx.x & 63;
    float x0 = x[node * 4 + 0], x1 = x[node * 4 + 1];
    float x2 = x[node * 4 + 2], x3 = x[node * 4 + 3];
    float h = x0 * W1[lane] + x1 * W1[64 + lane] + x2 * W1[128 + lane] + x3 * W1[192 + lane];
    h1h[(size_t)node * 64 + lane] = __float2half(h);
    float as = h * a_src1[lane];
    float ad = h * a_dst1[lane];
#pragma unroll
    for (int m = 8; m >= 1; m >>= 1) {
        as += __shfl_xor(as, m, 16);
        ad += __shfl_xor(ad, m, 16);
    }
    if ((lane & 15) == 0) {
        int head = lane >> 4;
        as1[node * 4 + head] = as;
        ad1[node * 4 + head] = ad;
    }
}

// ---------------- p1hist: 256 blocks x 1024 thr (16 waves/CU) ----------------
__global__ void k_p1hist(const int* __restrict__ dst, int* __restrict__ histT,
                         int E, int chunk, int nbucket) {
    __shared__ int cnt[512];
    int blk = blockIdx.x, t = threadIdx.x;
    for (int i = t; i < nbucket; i += P1S_THREADS) cnt[i] = 0;
    __syncthreads();
    int s = blk * chunk, e = min(E, s + chunk);
    for (int i = s + t; i < e; i += P1S_THREADS)
        atomicAdd(&cnt[dst[i] >> 8], 1);
    __syncthreads();
    for (int i = t; i < nbucket; i += P1S_THREADS)
        histT[i * P1_NB + blk] = cnt[i];                 // bin-major
}

// exclusive scan, 2048 elems per block (256 thr x 8); baseT is scan-block-LOCAL,
// consumers add prefix of blockSums themselves (no scan23 dispatch).
__global__ void k_scan1(const int* __restrict__ in, int* __restrict__ out,
                        int* __restrict__ blockSums, int M) {
    __shared__ int sdata[256];
    int t = threadIdx.x;
    int base = blockIdx.x * 2048 + t * 8;
    int v[8];
    int total = 0;
#pragma unroll
    for (int k = 0; k < 8; ++k) {
        int idx = base + k;
        v[k] = (idx < M) ? in[idx] : 0;
        total += v[k];
    }
    sdata[t] = total;
    __syncthreads();
    for (int off = 1; off < 256; off <<= 1) {
        int x = (t >= off) ? sdata[t - off] : 0;
        __syncthreads();
        sdata[t] += x;
        __syncthreads();
    }
    int run = sdata[t] - total;
#pragma unroll
    for (int k = 0; k < 8; ++k) {
        int idx = base + k;
        if (idx < M) out[idx] = run;
        run += v[k];
    }
    if (t == 255) blockSums[blockIdx.x] = sdata[255];
}

// 1024 threads: builds 49-entry prefix table of blockSums in LDS, then scatters.
__global__ void k_p1scatter(const int* __restrict__ src, const int* __restrict__ dst,
                            const int* __restrict__ baseT, const int* __restrict__ blockSums,
                            int nbScan, unsigned int* __restrict__ packed,
                            int E, int chunk, int nbucket) {
    __shared__ int cnt[512];
    __shared__ int pre[64];
    int blk = blockIdx.x, t = threadIdx.x;
    if (t == 0) {
        int run = 0;
        for (int j = 0; j < nbScan; ++j) { pre[j] = run; run += blockSums[j]; }
    }
    __syncthreads();
    for (int i = t; i < nbucket; i += P1S_THREADS) {
        int idx = i * P1_NB + blk;
        cnt[i] = baseT[idx] + pre[idx >> SCAN_SHIFT];
    }
    __syncthreads();
    int s = blk * chunk, e = min(E, s + chunk);
    for (int i = s + t; i < e; i += P1S_THREADS) {
        int d = dst[i];
        int pos = atomicAdd(&cnt[d >> 8], 1);            // LDS atomic
        packed[pos] = ((unsigned int)(d & 255) << 23) | (unsigned int)src[i];
    }
}

// ---------------- Fused fine + layer1: one block per bucket (391 x 1024 thr) --------
__global__ void k_fineL1(const unsigned int* __restrict__ packed, const int* __restrict__ baseT,
                         const int* __restrict__ blockSums, int nbScan,
                         const __half* __restrict__ h1h, const float* __restrict__ as1,
                         const float* __restrict__ ad1, const float* __restrict__ b1,
                         const float* __restrict__ W2, const float* __restrict__ a_src2,
                         const float* __restrict__ a_dst2,
                         int* __restrict__ csr, int* __restrict__ rowptr,
                         uint2* __restrict__ node2, int N, int E) {
    __shared__ int cnt[256];                 // per-local degree (preserved)
    __shared__ int off[256];                 // per-local exclusive offset (preserved)
    __shared__ int cur[256];                 // scratch: scan + placement cursor
    __shared__ int sePre[2];
    __shared__ unsigned int eb[MAX_BEDGES];  // bucket edges sorted by local

    int b = blockIdx.x, t = threadIdx.x;
    int nbucket = gridDim.x;
    if (t == 0) {
        int idx0 = b * P1_NB, idx1 = (b + 1) * P1_NB;
        int sb0 = idx0 >> SCAN_SHIFT, sb1 = idx1 >> SCAN_SHIFT;
        int run = 0, p0 = 0, p1 = 0;
        for (int j = 0; j < nbScan; ++j) {
            if (j == sb0) p0 = run;
            if (j == sb1) p1 = run;
            run += blockSums[j];
        }
        sePre[0] = p0; sePre[1] = p1;
    }
    if (t < 256) cnt[t] = 0;
    __syncthreads();
    int startE = baseT[b * P1_NB] + sePre[0];
    int endE = E;
    if (b != nbucket - 1) endE = baseT[(b + 1) * P1_NB] + sePre[1];
    int ne = endE - startE;
    if (ne > MAX_BEDGES) ne = MAX_BEDGES;    // statistically impossible (~23 sigma)

    for (int i = t; i < ne; i += 1024)
        atomicAdd(&cnt[packed[startE + i] >> 23], 1);
    __syncthreads();
    if (t < 256) cur[t] = cnt[t];
    __syncthreads();
    for (int o = 1; o < 256; o <<= 1) {
        int v = (t < 256 && t >= o) ? cur[t - o] : 0;
        __syncthreads();
        if (t < 256) cur[t] += v;
        __syncthreads();
    }
    if (t < 256) {
        int excl = cur[t] - cnt[t];
        off[t] = excl;
        int node = (b << 8) + t;
        if (node < N) rowptr[node] = startE + excl;
    }
    if (b == 0 && t == 0) rowptr[N] = E;
    __syncthreads();
    if (t < 256) cur[t] = off[t];
    __syncthreads();
    for (int i = t; i < ne; i += 1024) {
        unsigned int p = packed[startE + i];
        int pos = atomicAdd(&cur[p >> 23], 1);
        eb[pos] = p;
    }
    __syncthreads();
    // sequential csr writeout (consumed by k_layer2)
    for (int i = t; i < ne; i += 1024)
        csr[startE + i] = (int)(eb[i] & 0x7FFFFFu);

    // ---- layer1 over this bucket's 256 nodes (16 waves x 16 locals) ----
    int wave = t >> 6;           // 0..15
    int lane = t & 63;
    int head4 = lane & 3;        // stage-1 head
    int j     = lane >> 2;       // stage-1 edge slot (0..15)
    int sub   = lane >> 4;       // stage-2 edge subgroup (0..3)
    int fl    = lane & 15;       // stage-2 feature quad
    int h     = fl >> 2;         // stage-2 head
    int nodeBase = b << 8;

    for (int q = 0; q < 16; ++q) {
        int local = wave * 16 + q;
        int node = nodeBase + local;
        if (node >= N) break;    // wave-uniform (only last bucket)
        int beg = off[local];
        int end = beg + cnt[local];

        float ad_s1 = ad1[node * 4 + head4];
        float pself4 = __expf(leaky(as1[node * 4 + head4] + ad_s1));
        float psum = (lane < 4) ? pself4 : 0.f;

        float pselfF = __shfl(pself4, h);
        float a0 = 0.f, a1 = 0.f, a2 = 0.f, a3 = 0.f;
        if (sub == 0) {
            float2 raw = *(const float2*)(h1h + ((size_t)node << 6) + (fl << 2));
            __half2 h01 = *reinterpret_cast<__half2*>(&raw.x);
            __half2 h23 = *reinterpret_cast<__half2*>(&raw.y);
            float2 f01 = __half22float2(h01), f23 = __half22float2(h23);
            a0 = pselfF * f01.x; a1 = pselfF * f01.y;
            a2 = pselfF * f23.x; a3 = pselfF * f23.y;
        }

        for (int c = beg; c < end; c += 16) {
            int e = c + j;
            bool valid = e < end;
            int s = (int)(eb[valid ? e : beg] & 0x7FFFFFu);   // LDS broadcast read
            float v = leaky(as1[s * 4 + head4] + ad_s1);
            float p = valid ? __expf(v) : 0.f;
            psum += p;

            int s_q[4];
#pragma unroll
            for (int m = 0; m < 4; ++m) s_q[m] = __shfl(s, m * 16 + sub * 4);
            float2 raw[4];
#pragma unroll
            for (int m = 0; m < 4; ++m)
                raw[m] = *(const float2*)(h1h + ((size_t)s_q[m] << 6) + (fl << 2));
            float p_q[4];
#pragma unroll
            for (int m = 0; m < 4; ++m) p_q[m] = __shfl(p, m * 16 + sub * 4 + h);
#pragma unroll
            for (int m = 0; m < 4; ++m) {
                __half2 h01 = *reinterpret_cast<__half2*>(&raw[m].x);
                __half2 h23 = *reinterpret_cast<__half2*>(&raw[m].y);
                float2 f01 = __half22float2(h01), f23 = __half22float2(h23);
                a0 = fmaf(p_q[m], f01.x, a0);
                a1 = fmaf(p_q[m], f01.y, a1);
                a2 = fmaf(p_q[m], f23.x, a2);
                a3 = fmaf(p_q[m], f23.y, a3);
            }
        }

        a0 += __shfl_xor(a0, 16); a0 += __shfl_xor(a0, 32);
        a1 += __shfl_xor(a1, 16); a1 += __shfl_xor(a1, 32);
        a2 += __shfl_xor(a2, 16); a2 += __shfl_xor(a2, 32);
        a3 += __shfl_xor(a3, 16); a3 += __shfl_xor(a3, 32);

#pragma unroll
        for (int m = 4; m <= 32; m <<= 1) psum += __shfl_xor(psum, m);
        float psumF = __shfl(psum, h);
        float inv = 1.f / (psumF + EPS_F);

        float4 b1v = ((const float4*)b1)[fl];
        float o0 = a0 * inv + b1v.x;
        float o1 = a1 * inv + b1v.y;
        float o2 = a2 * inv + b1v.z;
        float o3 = a3 * inv + b1v.w;
        // cheap ELU: for o<0, exp(o)<=1 so __expf(o)-1 abs err ~1e-8
        float e0 = o0 > 0.f ? o0 : (__expf(o0) - 1.f);
        float e1 = o1 > 0.f ? o1 : (__expf(o1) - 1.f);
        float e2 = o2 > 0.f ? o2 : (__expf(o2) - 1.f);
        float e3 = o3 > 0.f ? o3 : (__expf(o3) - 1.f);

        float4 w01 = ((const float4*)W2)[fl * 2];
        float4 w23 = ((const float4*)W2)[fl * 2 + 1];
        float c0 = e0 * w01.x + e1 * w01.z + e2 * w23.x + e3 * w23.z;
        float c1 = e0 * w01.y + e1 * w01.w + e2 * w23.y + e3 * w23.w;
#pragma unroll
        for (int m = 8; m >= 1; m >>= 1) {
            c0 += __shfl_xor(c0, m);
            c1 += __shfl_xor(c1, m);
        }
        if (lane == 0) {
            float as2 = c0 * a_src2[0] + c1 * a_src2[1];
            float ad2 = c0 * a_dst2[0] + c1 * a_dst2[1];
            __half2 hc = __floats2half2_rn(c0, c1);
            __half2 ha = __floats2half2_rn(as2, ad2);
            node2[node] = make_uint2(*(unsigned int*)&hc, *(unsigned int*)&ha);
        }
    }
}

// ---------------- Layer 2: 16 lanes per node (4 nodes/wave), fp16 node2, fused log_softmax ----
__global__ void k_layer2(const int* __restrict__ rowptr, const int* __restrict__ csr,
                         const uint2* __restrict__ node2, const float* __restrict__ b2,
                         float* __restrict__ out, int N) {
    int node = blockIdx.x * 16 + (threadIdx.x >> 4);
    if (node >= N) return;
    int sl = threadIdx.x & 15;

    uint2 mraw = node2[node];
    __half2 mch = *reinterpret_cast<__half2*>(&mraw.x);
    __half2 mah = *reinterpret_cast<__half2*>(&mraw.y);
    float2 mc = __half22float2(mch);   // c0, c1
    float2 ma = __half22float2(mah);   // as2, ad2
    float ad = ma.y;
    int beg = rowptr[node], end = rowptr[node + 1];

    float psum = 0.f, a0 = 0.f, a1 = 0.f;
    for (int e = beg + sl; e < end; e += 16) {
        uint2 sraw = node2[csr[e]];
        __half2 sch = *reinterpret_cast<__half2*>(&sraw.x);
        __half2 sah = *reinterpret_cast<__half2*>(&sraw.y);
        float2 sc = __half22float2(sch);
        float2 sa = __half22float2(sah);
        float p = __expf(leaky(sa.x + ad));
        psum += p;
        a0 = fmaf(p, sc.x, a0);
        a1 = fmaf(p, sc.y, a1);
    }
    if (sl == 0) {
        float p = __expf(leaky(ma.x + ad));       // self loop
        psum += p;
        a0 = fmaf(p, mc.x, a0);
        a1 = fmaf(p, mc.y, a1);
    }
#pragma unroll
    for (int m = 8; m >= 1; m >>= 1) {
        psum += __shfl_xor(psum, m);
        a0 += __shfl_xor(a0, m);
        a1 += __shfl_xor(a1, m);
    }
    if (sl == 0) {
        float inv = 1.f / (psum + EPS_F);
        float o0 = a0 * inv + b2[0];
        float o1 = a1 * inv + b2[1];
        float mx = fmaxf(o0, o1);
        float lse = mx + logf(__expf(o0 - mx) + __expf(o1 - mx));
        out[node * 2 + 0] = o0 - lse;
        out[node * 2 + 1] = o1 - lse;
    }
}

// ---------------- launch ----------------

extern "C" void kernel_launch(void* const* d_in, const int* in_sizes, int n_in,
                              void* d_out, int out_size, void* d_ws, size_t ws_size,
                              hipStream_t stream) {
    const float* x      = (const float*)d_in[0];
    const int*   ei     = (const int*)d_in[1];
    const float* W1     = (const float*)d_in[2];
    const float* a_src1 = (const float*)d_in[3];
    const float* a_dst1 = (const float*)d_in[4];
    const float* b1     = (const float*)d_in[5];
    const float* W2     = (const float*)d_in[6];
    const float* a_src2 = (const float*)d_in[7];
    const float* a_dst2 = (const float*)d_in[8];
    const float* b2     = (const float*)d_in[9];
    float* out = (float*)d_out;

    int N = in_sizes[0] / 4;
    int E = in_sizes[1] / 2;
    const int* e_src = ei;
    const int* e_dst = ei + E;

    int nbucket = (N + 255) >> 8;               // 391 for N=100000 (<=512)
    int M = nbucket * P1_NB;                    // 100096

    char* w = (char*)d_ws;
    auto alloc = [&](size_t bytes) -> void* {
        void* p = (void*)w;
        w += (bytes + 255) & ~(size_t)255;
        return p;
    };
    __half* h1h       = (__half*)alloc((size_t)N * 64 * 2);
    float*  as1       = (float*)alloc((size_t)N * 4 * 4);
    float*  ad1       = (float*)alloc((size_t)N * 4 * 4);
    uint2*  node2     = (uint2*)alloc((size_t)N * 8);
    int*    rowptr    = (int*)alloc((size_t)(N + 1) * 4);
    int*    histT     = (int*)alloc((size_t)M * 4);
    int*    baseT     = (int*)alloc((size_t)M * 4);
    int*    blockSums = (int*)alloc(256 * 4);
    int*    csr       = (int*)alloc((size_t)E * 4);
    unsigned int* packed = (unsigned int*)alloc((size_t)E * 4);

    int chunk = (E + P1_NB - 1) / P1_NB;        // 12500
    int nbScan = (M + 2047) / 2048;             // 49 (<=64 for LDS pre-table)
    int nodeb = (N + 3) / 4;                    // 25000

    k_phaseA<<<nodeb, 256, 0, stream>>>(x, W1, a_src1, a_dst1, h1h, as1, ad1, N);
    k_p1hist<<<P1_NB, P1S_THREADS, 0, stream>>>(e_dst, histT, E, chunk, nbucket);
    k_scan1<<<nbScan, 256, 0, stream>>>(histT, baseT, blockSums, M);
    k_p1scatter<<<P1_NB, P1S_THREADS, 0, stream>>>(e_src, e_dst, baseT, blockSums, nbScan,
                                                   packed, E, chunk, nbucket);
    k_fineL1<<<nbucket, 1024, 0, stream>>>(packed, baseT, blockSums, nbScan,
                                           h1h, as1, ad1, b1, W2,
                                           a_src2, a_dst2, csr, rowptr, node2, N, E);
    k_layer2<<<(N + 15) / 16, 256, 0, stream>>>(rowptr, csr, node2, b2, out, N);
}